// Round 1
// baseline (1479.473 us; speedup 1.0000x reference)
//
#include <hip/hip_runtime.h>
#include <hip/hip_bf16.h>

#define B_ 8
#define C_ 256
#define N_ 4096
#define D_ 64

typedef __attribute__((ext_vector_type(8))) short bf16x8;
typedef __attribute__((ext_vector_type(4))) float f32x4;

__device__ __forceinline__ float bf2f(unsigned short h){
    return __uint_as_float(((unsigned int)h) << 16);
}
__device__ __forceinline__ unsigned short f2bf(float f){
    unsigned int u = __float_as_uint(f);
    u += 0x7FFFu + ((u >> 16) & 1u);
    return (unsigned short)(u >> 16);
}
__device__ __forceinline__ bf16x8 ldf(const unsigned short* p){
    return *(const bf16x8*)p;
}
__device__ __forceinline__ f32x4 mfma_bf16(bf16x8 a, bf16x8 b, f32x4 c){
    return __builtin_amdgcn_mfma_f32_16x16x32_bf16(a, b, c, 0, 0, 0);
}

// ---------------------------------------------------------------------------
// x [B,C,N] fp32 -> xhT/xlT [B,N,C] bf16 hi/lo (split for accurate QK proj)
__global__ __launch_bounds__(256) void convert_x_kernel(
    const float* __restrict__ x,
    unsigned short* __restrict__ xhT, unsigned short* __restrict__ xlT)
{
    __shared__ float tile[64][65];
    int b = blockIdx.z, c0 = blockIdx.y * 64, n0 = blockIdx.x * 64;
    int tid = threadIdx.x;
    int cc = tid & 63, rb = tid >> 6;
    #pragma unroll
    for (int j = 0; j < 16; j++){
        int rr = rb + 4*j;  // c offset
        tile[rr][cc] = x[((size_t)(b*C_ + c0 + rr))*N_ + n0 + cc];
    }
    __syncthreads();
    #pragma unroll
    for (int j = 0; j < 16; j++){
        int rr = rb + 4*j;  // n offset
        float v = tile[cc][rr];
        unsigned short h = f2bf(v);
        unsigned short l = f2bf(v - bf2f(h));
        size_t o = ((size_t)(b*N_ + n0 + rr))*C_ + c0 + cc;
        xhT[o] = h; xlT[o] = l;
    }
}

// Weights -> bf16 (Wqk split hi/lo)
__global__ __launch_bounds__(256) void convert_w_kernel(
    const float* __restrict__ Wqk, const float* __restrict__ Wv, const float* __restrict__ Wt,
    unsigned short* __restrict__ Wqk_hi, unsigned short* __restrict__ Wqk_lo,
    unsigned short* __restrict__ Wv_b, unsigned short* __restrict__ Wt_b)
{
    int i = blockIdx.x * 256 + threadIdx.x;
    if (i < D_*C_){
        float v = Wqk[i];
        unsigned short h = f2bf(v);
        Wqk_hi[i] = h; Wqk_lo[i] = f2bf(v - bf2f(h));
    }
    int j = i - D_*C_;
    if (j >= 0 && j < C_*C_) Wv_b[j] = f2bf(Wv[j]);
    int k = j - C_*C_;
    if (k >= 0 && k < C_*C_) Wt_b[k] = f2bf(Wt[k]);
}

// ---------------------------------------------------------------------------
// qk[b,n,d] = sum_c Wqk[d,c] x[b,c,n]  (split-bf16, 3-term). Out: [B,N,64] hi/lo
__global__ __launch_bounds__(256) void proj_qk_kernel(
    const unsigned short* __restrict__ xhT, const unsigned short* __restrict__ xlT,
    const unsigned short* __restrict__ Wh,  const unsigned short* __restrict__ Wl,
    unsigned short* __restrict__ qh, unsigned short* __restrict__ ql)
{
    int b = blockIdx.z, n0 = blockIdx.x * 64;
    int tid = threadIdx.x, w = tid >> 6, lane = tid & 63, q = lane >> 4, r = lane & 15;
    f32x4 z = {0.f,0.f,0.f,0.f};
    f32x4 acc[4] = {z,z,z,z};
    const unsigned short* Ah = Wh + (size_t)(16*w + r)*C_;
    const unsigned short* Al = Wl + (size_t)(16*w + r)*C_;
    const unsigned short* Bh = xhT + ((size_t)(b*N_ + n0 + r))*C_;
    const unsigned short* Bl = xlT + ((size_t)(b*N_ + n0 + r))*C_;
    for (int k0 = 0; k0 < C_; k0 += 32){
        bf16x8 ah = ldf(Ah + k0 + 8*q);
        bf16x8 al = ldf(Al + k0 + 8*q);
        #pragma unroll
        for (int f = 0; f < 4; f++){
            bf16x8 bh = ldf(Bh + (size_t)(16*f)*C_ + k0 + 8*q);
            bf16x8 bl = ldf(Bl + (size_t)(16*f)*C_ + k0 + 8*q);
            acc[f] = mfma_bf16(ah, bh, acc[f]);
            acc[f] = mfma_bf16(ah, bl, acc[f]);
            acc[f] = mfma_bf16(al, bh, acc[f]);
        }
    }
    #pragma unroll
    for (int f = 0; f < 4; f++){
        int col = n0 + 16*f + r;
        int d0 = 16*w + 4*q;
        size_t o = ((size_t)(b*N_ + col))*D_ + d0;
        ushort4 hv, lv;
        float v0 = acc[f][0], v1 = acc[f][1], v2 = acc[f][2], v3 = acc[f][3];
        hv.x = f2bf(v0); lv.x = f2bf(v0 - bf2f(hv.x));
        hv.y = f2bf(v1); lv.y = f2bf(v1 - bf2f(hv.y));
        hv.z = f2bf(v2); lv.z = f2bf(v2 - bf2f(hv.z));
        hv.w = f2bf(v3); lv.w = f2bf(v3 - bf2f(hv.w));
        *(ushort4*)(qh + o) = hv;
        *(ushort4*)(ql + o) = lv;
    }
}

// x_v[b,d,n] = sum_c Wv[d,c] x[b,c,n] + bv[d].  Out: xvb [B,C,N] bf16
__global__ __launch_bounds__(256) void proj_v_kernel(
    const unsigned short* __restrict__ xhT, const unsigned short* __restrict__ Wvb,
    const float* __restrict__ bv, unsigned short* __restrict__ xvb)
{
    int b = blockIdx.z, n0 = blockIdx.x * 64, d0 = blockIdx.y * 64;
    int tid = threadIdx.x, w = tid >> 6, lane = tid & 63, q = lane >> 4, r = lane & 15;
    f32x4 z = {0.f,0.f,0.f,0.f};
    f32x4 acc[4] = {z,z,z,z};
    const unsigned short* A = Wvb + (size_t)(d0 + 16*w + r)*C_;
    const unsigned short* Bb = xhT + ((size_t)(b*N_ + n0 + r))*C_;
    for (int k0 = 0; k0 < C_; k0 += 32){
        bf16x8 a = ldf(A + k0 + 8*q);
        #pragma unroll
        for (int f = 0; f < 4; f++){
            bf16x8 bb = ldf(Bb + (size_t)(16*f)*C_ + k0 + 8*q);
            acc[f] = mfma_bf16(a, bb, acc[f]);
        }
    }
    #pragma unroll
    for (int f = 0; f < 4; f++){
        int col = n0 + 16*f + r;
        #pragma unroll
        for (int i = 0; i < 4; i++){
            int row = d0 + 16*w + 4*q + i;
            float v = acc[f][i] + bv[row];
            xvb[((size_t)(b*C_ + row))*N_ + col] = f2bf(v);
        }
    }
}

// energy[n,m] = q_n . q_m (split-bf16, 3-term), per batch. Out fp32 [N,N]
__global__ __launch_bounds__(256) void energy_kernel(
    const unsigned short* __restrict__ qh, const unsigned short* __restrict__ ql,
    float* __restrict__ energy)
{
    int m0 = blockIdx.x * 64, n0 = blockIdx.y * 64;
    int tid = threadIdx.x, w = tid >> 6, lane = tid & 63, q = lane >> 4, r = lane & 15;
    f32x4 z = {0.f,0.f,0.f,0.f};
    f32x4 acc[4] = {z,z,z,z};
    const unsigned short* Ah = qh + (size_t)(n0 + 16*w + r)*D_;
    const unsigned short* Al = ql + (size_t)(n0 + 16*w + r)*D_;
    #pragma unroll
    for (int k0 = 0; k0 < D_; k0 += 32){
        bf16x8 ah = ldf(Ah + k0 + 8*q);
        bf16x8 al = ldf(Al + k0 + 8*q);
        #pragma unroll
        for (int f = 0; f < 4; f++){
            bf16x8 bh = ldf(qh + (size_t)(m0 + 16*f + r)*D_ + k0 + 8*q);
            bf16x8 bl = ldf(ql + (size_t)(m0 + 16*f + r)*D_ + k0 + 8*q);
            acc[f] = mfma_bf16(ah, bh, acc[f]);
            acc[f] = mfma_bf16(ah, bl, acc[f]);
            acc[f] = mfma_bf16(al, bh, acc[f]);
        }
    }
    #pragma unroll
    for (int f = 0; f < 4; f++){
        #pragma unroll
        for (int i = 0; i < 4; i++){
            int row = n0 + 16*w + 4*q + i;
            energy[(size_t)row*N_ + m0 + 16*f + r] = acc[f][i];
        }
    }
}

// per-row max and sum(exp(e-max)) over a full row of energy
__global__ __launch_bounds__(256) void rowstats_kernel(
    const float* __restrict__ energy, float* __restrict__ rmax, float* __restrict__ rsum)
{
    __shared__ float red[8];
    int row = blockIdx.x, tid = threadIdx.x, w = tid >> 6, lane = tid & 63;
    const float* p = energy + (size_t)row*N_;
    float mx = -1e30f;
    for (int j = tid; j < N_; j += 256) mx = fmaxf(mx, p[j]);
    for (int o = 32; o > 0; o >>= 1) mx = fmaxf(mx, __shfl_xor(mx, o));
    if (lane == 0) red[w] = mx;
    __syncthreads();
    mx = fmaxf(fmaxf(red[0], red[1]), fmaxf(red[2], red[3]));
    float s = 0.f;
    for (int j = tid; j < N_; j += 256) s += __expf(p[j] - mx);
    for (int o = 32; o > 0; o >>= 1) s += __shfl_xor(s, o);
    if (lane == 0) red[4 + w] = s;
    __syncthreads();
    if (tid == 0){ rmax[row] = mx; rsum[row] = red[4] + red[5] + red[6] + red[7]; }
}

// A = softmax rows; accumulate colsum; write A^T bf16 [m][n]
__global__ __launch_bounds__(256) void softmax_t_kernel(
    const float* __restrict__ energy, const float* __restrict__ rmax,
    const float* __restrict__ rsum, float* __restrict__ colsum,
    unsigned short* __restrict__ AT)
{
    __shared__ unsigned short tile[64][66];
    int m0 = blockIdx.x * 64, n0 = blockIdx.y * 64;
    int tid = threadIdx.x, cc = tid & 63, rb = tid >> 6;
    float csum = 0.f;
    #pragma unroll
    for (int j = 0; j < 16; j++){
        int rr = rb + 4*j;
        int row = n0 + rr;
        float e = energy[(size_t)row*N_ + m0 + cc];
        float a = __expf(e - rmax[row]) * (1.0f / rsum[row]);
        csum += a;
        tile[rr][cc] = f2bf(a);
    }
    atomicAdd(&colsum[m0 + cc], csum);
    __syncthreads();
    #pragma unroll
    for (int j = 0; j < 16; j++){
        int mm = rb + 4*j;
        AT[(size_t)(m0 + mm)*N_ + n0 + cc] = tile[cc][mm];
    }
}

// x_r[c,m] = (sum_n xv[c,n] A[n,m]) / (1e-9+colsum[m]); u = x - x_r -> uT [N,C] bf16
__global__ __launch_bounds__(256) void xr_kernel(
    const unsigned short* __restrict__ xvb_b, const unsigned short* __restrict__ AT,
    const float* __restrict__ colsum, const float* __restrict__ x_b,
    unsigned short* __restrict__ uT_b)
{
    int m0 = blockIdx.x * 64, c0 = blockIdx.y * 64;
    int tid = threadIdx.x, w = tid >> 6, lane = tid & 63, q = lane >> 4, r = lane & 15;
    f32x4 z = {0.f,0.f,0.f,0.f};
    f32x4 acc[4] = {z,z,z,z};
    const unsigned short* A = xvb_b + (size_t)(c0 + 16*w + r)*N_;
    for (int k0 = 0; k0 < N_; k0 += 32){
        bf16x8 a = ldf(A + k0 + 8*q);
        #pragma unroll
        for (int f = 0; f < 4; f++){
            bf16x8 bb = ldf(AT + (size_t)(m0 + 16*f + r)*N_ + k0 + 8*q);
            acc[f] = mfma_bf16(a, bb, acc[f]);
        }
    }
    #pragma unroll
    for (int f = 0; f < 4; f++){
        int col = m0 + 16*f + r;
        float sc = 1.0f / (1e-9f + colsum[col]);
        int row0 = c0 + 16*w + 4*q;
        ushort4 uv;
        float u0 = x_b[(size_t)(row0+0)*N_ + col] - acc[f][0]*sc;
        float u1 = x_b[(size_t)(row0+1)*N_ + col] - acc[f][1]*sc;
        float u2 = x_b[(size_t)(row0+2)*N_ + col] - acc[f][2]*sc;
        float u3 = x_b[(size_t)(row0+3)*N_ + col] - acc[f][3]*sc;
        uv.x = f2bf(u0); uv.y = f2bf(u1); uv.z = f2bf(u2); uv.w = f2bf(u3);
        *(ushort4*)(uT_b + (size_t)col*C_ + row0) = uv;
    }
}

// t[b,d,n] = sum_c Wt[d,c] u[b,c,n]  (bias bt cancels in training-mode BN)
// Out tT [B*N, C] fp32
__global__ __launch_bounds__(256) void t_kernel(
    const unsigned short* __restrict__ uT, const unsigned short* __restrict__ Wtb,
    float* __restrict__ tT)
{
    int b = blockIdx.z, n0 = blockIdx.x * 64, d0 = blockIdx.y * 64;
    int tid = threadIdx.x, w = tid >> 6, lane = tid & 63, q = lane >> 4, r = lane & 15;
    f32x4 z = {0.f,0.f,0.f,0.f};
    f32x4 acc[4] = {z,z,z,z};
    const unsigned short* A = Wtb + (size_t)(d0 + 16*w + r)*C_;
    const unsigned short* Bb = uT + ((size_t)(b*N_ + n0 + r))*C_;
    for (int k0 = 0; k0 < C_; k0 += 32){
        bf16x8 a = ldf(A + k0 + 8*q);
        #pragma unroll
        for (int f = 0; f < 4; f++){
            bf16x8 bb = ldf(Bb + (size_t)(16*f)*C_ + k0 + 8*q);
            acc[f] = mfma_bf16(a, bb, acc[f]);
        }
    }
    #pragma unroll
    for (int f = 0; f < 4; f++){
        int col = n0 + 16*f + r;
        int row0 = d0 + 16*w + 4*q;
        float4 v;
        v.x = acc[f][0]; v.y = acc[f][1]; v.z = acc[f][2]; v.w = acc[f][3];
        *(float4*)(tT + ((size_t)(b*N_ + col))*C_ + row0) = v;
    }
}

__global__ __launch_bounds__(256) void bn_stats_kernel(
    const float* __restrict__ tT, float* __restrict__ bnsum, float* __restrict__ bnsq)
{
    int d = threadIdx.x;
    int r0 = blockIdx.x * 128;
    float s = 0.f, s2 = 0.f;
    for (int j = 0; j < 128; j++){
        float v = tT[(size_t)(r0 + j)*C_ + d];
        s += v; s2 += v*v;
    }
    atomicAdd(&bnsum[d], s);
    atomicAdd(&bnsq[d], s2);
}

__global__ __launch_bounds__(256) void bn_final_kernel(
    const float* __restrict__ bnsum, const float* __restrict__ bnsq,
    const float* __restrict__ gamma, const float* __restrict__ beta,
    float* __restrict__ scale, float* __restrict__ shift)
{
    int d = threadIdx.x;
    const float inv = 1.0f / (B_ * N_);
    float m = bnsum[d] * inv;
    float v = bnsq[d] * inv - m*m;
    float rs = rsqrtf(v + 1e-5f);
    float sc = gamma[d] * rs;
    scale[d] = sc;
    shift[d] = beta[d] - m*sc;
}

// out[b,d,n] = x + relu(tT[b,n,d]*scale[d] + shift[d])  (transpose via LDS)
__global__ __launch_bounds__(256) void final_kernel(
    const float* __restrict__ tT, const float* __restrict__ x,
    const float* __restrict__ scale, const float* __restrict__ shift,
    float* __restrict__ out)
{
    __shared__ float tile[64][65];
    int b = blockIdx.z, n0 = blockIdx.x * 64, d0 = blockIdx.y * 64;
    int tid = threadIdx.x, cc = tid & 63, rb = tid >> 6;
    #pragma unroll
    for (int j = 0; j < 16; j++){
        int rr = rb + 4*j;  // n offset
        tile[rr][cc] = tT[((size_t)(b*N_ + n0 + rr))*C_ + d0 + cc];
    }
    __syncthreads();
    #pragma unroll
    for (int j = 0; j < 16; j++){
        int mm = rb + 4*j;  // d offset
        int d = d0 + mm;
        float tv = tile[cc][mm] * scale[d] + shift[d];
        tv = fmaxf(tv, 0.0f);
        size_t o = ((size_t)(b*C_ + d))*N_ + n0 + cc;
        out[o] = x[o] + tv;
    }
}

// ---------------------------------------------------------------------------
extern "C" void kernel_launch(void* const* d_in, const int* in_sizes, int n_in,
                              void* d_out, int out_size, void* d_ws, size_t ws_size,
                              hipStream_t stream)
{
    const float* x     = (const float*)d_in[0];
    const float* Wqk   = (const float*)d_in[1];
    const float* Wv    = (const float*)d_in[2];
    const float* bv    = (const float*)d_in[3];
    const float* Wt    = (const float*)d_in[4];
    // d_in[5] = bt : provably cancels through training-mode BatchNorm
    const float* gamma = (const float*)d_in[6];
    const float* beta  = (const float*)d_in[7];
    float* out = (float*)d_out;

    char* ws = (char*)d_ws;
    size_t off = 0;
    auto alloc = [&](size_t bytes) -> void* {
        void* p = ws + off;
        off += (bytes + 255) & ~(size_t)255;
        return p;
    };
    unsigned short* xhT    = (unsigned short*)alloc((size_t)B_*N_*C_*2);
    unsigned short* xlT    = (unsigned short*)alloc((size_t)B_*N_*C_*2);
    unsigned short* Wqk_hi = (unsigned short*)alloc((size_t)D_*C_*2);
    unsigned short* Wqk_lo = (unsigned short*)alloc((size_t)D_*C_*2);
    unsigned short* Wv_b   = (unsigned short*)alloc((size_t)C_*C_*2);
    unsigned short* Wt_b   = (unsigned short*)alloc((size_t)C_*C_*2);
    unsigned short* qh     = (unsigned short*)alloc((size_t)B_*N_*D_*2);
    unsigned short* ql     = (unsigned short*)alloc((size_t)B_*N_*D_*2);
    unsigned short* xvb    = (unsigned short*)alloc((size_t)B_*C_*N_*2);
    unsigned short* uT     = (unsigned short*)alloc((size_t)B_*N_*C_*2);
    float*          tT     = (float*)alloc((size_t)B_*N_*C_*4);
    float*          energy = (float*)alloc((size_t)N_*N_*4);
    unsigned short* AT     = (unsigned short*)alloc((size_t)N_*N_*2);
    float*          rmax   = (float*)alloc((size_t)N_*4);
    float*          rsum   = (float*)alloc((size_t)N_*4);
    float*          colsum = (float*)alloc((size_t)N_*4);
    float*          bnsum  = (float*)alloc(256*4);
    float*          bnsq   = (float*)alloc(256*4);
    float*          scale  = (float*)alloc(256*4);
    float*          shift  = (float*)alloc(256*4);

    convert_x_kernel<<<dim3(N_/64, C_/64, B_), 256, 0, stream>>>(x, xhT, xlT);
    convert_w_kernel<<<(D_*C_ + 2*C_*C_ + 255)/256, 256, 0, stream>>>(
        Wqk, Wv, Wt, Wqk_hi, Wqk_lo, Wv_b, Wt_b);
    proj_qk_kernel<<<dim3(N_/64, 1, B_), 256, 0, stream>>>(xhT, xlT, Wqk_hi, Wqk_lo, qh, ql);
    proj_v_kernel<<<dim3(N_/64, C_/64, B_), 256, 0, stream>>>(xhT, Wv_b, bv, xvb);

    for (int b = 0; b < B_; b++){
        const unsigned short* qh_b = qh + (size_t)b*N_*D_;
        const unsigned short* ql_b = ql + (size_t)b*N_*D_;
        energy_kernel<<<dim3(N_/64, N_/64), 256, 0, stream>>>(qh_b, ql_b, energy);
        rowstats_kernel<<<N_, 256, 0, stream>>>(energy, rmax, rsum);
        hipMemsetAsync(colsum, 0, N_*4, stream);
        softmax_t_kernel<<<dim3(N_/64, N_/64), 256, 0, stream>>>(energy, rmax, rsum, colsum, AT);
        xr_kernel<<<dim3(N_/64, C_/64), 256, 0, stream>>>(
            xvb + (size_t)b*C_*N_, AT, colsum, x + (size_t)b*C_*N_, uT + (size_t)b*N_*C_);
    }

    t_kernel<<<dim3(N_/64, C_/64, B_), 256, 0, stream>>>(uT, Wt_b, tT);
    hipMemsetAsync(bnsum, 0, 256*4, stream);
    hipMemsetAsync(bnsq, 0, 256*4, stream);
    bn_stats_kernel<<<(B_*N_)/128, 256, 0, stream>>>(tT, bnsum, bnsq);
    bn_final_kernel<<<1, 256, 0, stream>>>(bnsum, bnsq, gamma, beta, scale, shift);
    final_kernel<<<dim3(N_/64, C_/64, B_), 256, 0, stream>>>(tT, x, scale, shift, out);
}

// Round 2
// 819.625 us; speedup vs baseline: 1.8051x; 1.8051x over previous
//
#include <hip/hip_runtime.h>
#include <hip/hip_bf16.h>

#define B_ 8
#define C_ 256
#define N_ 4096
#define D_ 64
#define GROUP_ 4   // batches per attention group (AT sized for GROUP_ batches)

typedef __attribute__((ext_vector_type(8))) short bf16x8;
typedef __attribute__((ext_vector_type(4))) float f32x4;

__device__ __forceinline__ float bf2f(unsigned short h){
    return __uint_as_float(((unsigned int)h) << 16);
}
__device__ __forceinline__ unsigned short f2bf(float f){
    unsigned int u = __float_as_uint(f);
    u += 0x7FFFu + ((u >> 16) & 1u);
    return (unsigned short)(u >> 16);
}
__device__ __forceinline__ bf16x8 ldf(const unsigned short* p){
    return *(const bf16x8*)p;
}
__device__ __forceinline__ f32x4 mfma_bf16(bf16x8 a, bf16x8 b, f32x4 c){
    return __builtin_amdgcn_mfma_f32_16x16x32_bf16(a, b, c, 0, 0, 0);
}
// async global->LDS, 16B per lane; l must be wave-uniform (lane*16 appended by HW)
__device__ __forceinline__ void gld_lds16(const unsigned short* g, unsigned short* l){
    __builtin_amdgcn_global_load_lds(
        (const __attribute__((address_space(1))) unsigned int*)g,
        (__attribute__((address_space(3))) unsigned int*)l, 16, 0, 0);
}

// ---------------------------------------------------------------------------
// x [B,C,N] fp32 -> xhT/xlT [B,N,C] bf16 hi/lo
__global__ __launch_bounds__(256) void convert_x_kernel(
    const float* __restrict__ x,
    unsigned short* __restrict__ xhT, unsigned short* __restrict__ xlT)
{
    __shared__ float tile[64][65];
    int b = blockIdx.z, c0 = blockIdx.y * 64, n0 = blockIdx.x * 64;
    int tid = threadIdx.x;
    int cc = tid & 63, rb = tid >> 6;
    #pragma unroll
    for (int j = 0; j < 16; j++){
        int rr = rb + 4*j;
        tile[rr][cc] = x[((size_t)(b*C_ + c0 + rr))*N_ + n0 + cc];
    }
    __syncthreads();
    #pragma unroll
    for (int j = 0; j < 16; j++){
        int rr = rb + 4*j;
        float v = tile[cc][rr];
        unsigned short h = f2bf(v);
        unsigned short l = f2bf(v - bf2f(h));
        size_t o = ((size_t)(b*N_ + n0 + rr))*C_ + c0 + cc;
        xhT[o] = h; xlT[o] = l;
    }
}

__global__ __launch_bounds__(256) void convert_w_kernel(
    const float* __restrict__ Wqk, const float* __restrict__ Wv, const float* __restrict__ Wt,
    unsigned short* __restrict__ Wqk_hi, unsigned short* __restrict__ Wqk_lo,
    unsigned short* __restrict__ Wv_b, unsigned short* __restrict__ Wt_b)
{
    int i = blockIdx.x * 256 + threadIdx.x;
    if (i < D_*C_){
        float v = Wqk[i];
        unsigned short h = f2bf(v);
        Wqk_hi[i] = h; Wqk_lo[i] = f2bf(v - bf2f(h));
    }
    int j = i - D_*C_;
    if (j >= 0 && j < C_*C_) Wv_b[j] = f2bf(Wv[j]);
    int k = j - C_*C_;
    if (k >= 0 && k < C_*C_) Wt_b[k] = f2bf(Wt[k]);
}

// qk[b,n,d]: split-bf16 3-term. Out [B,N,64] hi/lo
__global__ __launch_bounds__(256) void proj_qk_kernel(
    const unsigned short* __restrict__ xhT, const unsigned short* __restrict__ xlT,
    const unsigned short* __restrict__ Wh,  const unsigned short* __restrict__ Wl,
    unsigned short* __restrict__ qh, unsigned short* __restrict__ ql)
{
    int b = blockIdx.z, n0 = blockIdx.x * 64;
    int tid = threadIdx.x, w = tid >> 6, lane = tid & 63, q = lane >> 4, r = lane & 15;
    f32x4 z = {0.f,0.f,0.f,0.f};
    f32x4 acc[4] = {z,z,z,z};
    const unsigned short* Ah = Wh + (size_t)(16*w + r)*C_;
    const unsigned short* Al = Wl + (size_t)(16*w + r)*C_;
    const unsigned short* Bh = xhT + ((size_t)(b*N_ + n0 + r))*C_;
    const unsigned short* Bl = xlT + ((size_t)(b*N_ + n0 + r))*C_;
    for (int k0 = 0; k0 < C_; k0 += 32){
        bf16x8 ah = ldf(Ah + k0 + 8*q);
        bf16x8 al = ldf(Al + k0 + 8*q);
        #pragma unroll
        for (int f = 0; f < 4; f++){
            bf16x8 bh = ldf(Bh + (size_t)(16*f)*C_ + k0 + 8*q);
            bf16x8 bl = ldf(Bl + (size_t)(16*f)*C_ + k0 + 8*q);
            acc[f] = mfma_bf16(ah, bh, acc[f]);
            acc[f] = mfma_bf16(ah, bl, acc[f]);
            acc[f] = mfma_bf16(al, bh, acc[f]);
        }
    }
    #pragma unroll
    for (int f = 0; f < 4; f++){
        int col = n0 + 16*f + r;
        int d0 = 16*w + 4*q;
        size_t o = ((size_t)(b*N_ + col))*D_ + d0;
        ushort4 hv, lv;
        float v0 = acc[f][0], v1 = acc[f][1], v2 = acc[f][2], v3 = acc[f][3];
        hv.x = f2bf(v0); lv.x = f2bf(v0 - bf2f(hv.x));
        hv.y = f2bf(v1); lv.y = f2bf(v1 - bf2f(hv.y));
        hv.z = f2bf(v2); lv.z = f2bf(v2 - bf2f(hv.z));
        hv.w = f2bf(v3); lv.w = f2bf(v3 - bf2f(hv.w));
        *(ushort4*)(qh + o) = hv;
        *(ushort4*)(ql + o) = lv;
    }
}

// x_v[b,d,n] -> xvb [B,C,N] bf16
__global__ __launch_bounds__(256) void proj_v_kernel(
    const unsigned short* __restrict__ xhT, const unsigned short* __restrict__ Wvb,
    const float* __restrict__ bv, unsigned short* __restrict__ xvb)
{
    int b = blockIdx.z, n0 = blockIdx.x * 64, d0 = blockIdx.y * 64;
    int tid = threadIdx.x, w = tid >> 6, lane = tid & 63, q = lane >> 4, r = lane & 15;
    f32x4 z = {0.f,0.f,0.f,0.f};
    f32x4 acc[4] = {z,z,z,z};
    const unsigned short* A = Wvb + (size_t)(d0 + 16*w + r)*C_;
    const unsigned short* Bb = xhT + ((size_t)(b*N_ + n0 + r))*C_;
    for (int k0 = 0; k0 < C_; k0 += 32){
        bf16x8 a = ldf(A + k0 + 8*q);
        #pragma unroll
        for (int f = 0; f < 4; f++){
            bf16x8 bb = ldf(Bb + (size_t)(16*f)*C_ + k0 + 8*q);
            acc[f] = mfma_bf16(a, bb, acc[f]);
        }
    }
    #pragma unroll
    for (int f = 0; f < 4; f++){
        int col = n0 + 16*f + r;
        #pragma unroll
        for (int i = 0; i < 4; i++){
            int row = d0 + 16*w + 4*q + i;
            float v = acc[f][i] + bv[row];
            xvb[((size_t)(b*C_ + row))*N_ + col] = f2bf(v);
        }
    }
}

// ---------------------------------------------------------------------------
// Pass 1: flash-style row stats. Block owns 64 n-rows, sweeps all m tiles.
__global__ __launch_bounds__(256) void qk_stats_kernel(
    const unsigned short* __restrict__ qh, const unsigned short* __restrict__ ql,
    float* __restrict__ rmax, float* __restrict__ rsum)
{
    int b = blockIdx.y, n0 = blockIdx.x * 64;
    int tid = threadIdx.x, w = tid >> 6, lane = tid & 63, q = lane >> 4, r = lane & 15;
    const unsigned short* qb = qh + (size_t)b*N_*D_;
    const unsigned short* lb = ql + (size_t)b*N_*D_;
    const unsigned short* ap  = qb + (size_t)(n0 + 16*w + r)*D_ + 8*q;
    const unsigned short* alp = lb + (size_t)(n0 + 16*w + r)*D_ + 8*q;
    bf16x8 Ah0 = ldf(ap), Ah1 = ldf(ap + 32);
    bf16x8 Al0 = ldf(alp), Al1 = ldf(alp + 32);
    float rm[4] = {-1e30f,-1e30f,-1e30f,-1e30f};
    float rs[4] = {0.f,0.f,0.f,0.f};
    for (int m0 = 0; m0 < N_; m0 += 64){
        f32x4 z = {0.f,0.f,0.f,0.f};
        f32x4 acc[4] = {z,z,z,z};
        #pragma unroll
        for (int f = 0; f < 4; f++){
            const unsigned short* bp  = qb + (size_t)(m0 + 16*f + r)*D_ + 8*q;
            const unsigned short* blp = lb + (size_t)(m0 + 16*f + r)*D_ + 8*q;
            bf16x8 bh0 = ldf(bp), bh1 = ldf(bp+32);
            bf16x8 bl0 = ldf(blp), bl1 = ldf(blp+32);
            acc[f] = mfma_bf16(Ah0, bh0, acc[f]);
            acc[f] = mfma_bf16(Ah0, bl0, acc[f]);
            acc[f] = mfma_bf16(Al0, bh0, acc[f]);
            acc[f] = mfma_bf16(Ah1, bh1, acc[f]);
            acc[f] = mfma_bf16(Ah1, bl1, acc[f]);
            acc[f] = mfma_bf16(Al1, bh1, acc[f]);
        }
        #pragma unroll
        for (int i = 0; i < 4; i++){
            float mx = fmaxf(fmaxf(acc[0][i], acc[1][i]), fmaxf(acc[2][i], acc[3][i]));
            #pragma unroll
            for (int o = 1; o < 16; o <<= 1) mx = fmaxf(mx, __shfl_xor(mx, o));
            float nm = fmaxf(rm[i], mx);
            float s = __expf(acc[0][i]-nm) + __expf(acc[1][i]-nm)
                    + __expf(acc[2][i]-nm) + __expf(acc[3][i]-nm);
            #pragma unroll
            for (int o = 1; o < 16; o <<= 1) s += __shfl_xor(s, o);
            rs[i] = rs[i] * __expf(rm[i] - nm) + s;
            rm[i] = nm;
        }
    }
    if (r == 0){
        #pragma unroll
        for (int i = 0; i < 4; i++){
            int n = n0 + 16*w + 4*q + i;
            rmax[(size_t)b*N_ + n] = rm[i];
            rsum[(size_t)b*N_ + n] = rs[i];
        }
    }
}

// Pass 2: recompute energy, write A^T bf16 [m][n] + colsum (no atomics)
__global__ __launch_bounds__(256) void colsum_at_kernel(
    const unsigned short* __restrict__ qh, const unsigned short* __restrict__ ql,
    const float* __restrict__ rmax, const float* __restrict__ rsum,
    float* __restrict__ colsum, unsigned short* __restrict__ AT, int b0)
{
    __shared__ unsigned short tile[64*72];  // [m][n], stride 72 (16B-aligned rows)
    __shared__ float red[4][64];
    int bl = blockIdx.y, b = b0 + bl, m0 = blockIdx.x * 64;
    int tid = threadIdx.x, w = tid >> 6, lane = tid & 63, q = lane >> 4, r = lane & 15;
    const unsigned short* qb = qh + (size_t)b*N_*D_;
    const unsigned short* lb = ql + (size_t)b*N_*D_;
    bf16x8 Bh[4][2], Bl[4][2];
    #pragma unroll
    for (int f = 0; f < 4; f++){
        const unsigned short* bp  = qb + (size_t)(m0 + 16*f + r)*D_ + 8*q;
        const unsigned short* blp = lb + (size_t)(m0 + 16*f + r)*D_ + 8*q;
        Bh[f][0] = ldf(bp);  Bh[f][1] = ldf(bp+32);
        Bl[f][0] = ldf(blp); Bl[f][1] = ldf(blp+32);
    }
    float csum[4] = {0.f,0.f,0.f,0.f};
    unsigned short* ATb = AT + (size_t)bl*N_*N_;
    for (int ns = 0; ns < N_; ns += 64){
        const unsigned short* ap  = qb + (size_t)(ns + 16*w + r)*D_ + 8*q;
        const unsigned short* alp = lb + (size_t)(ns + 16*w + r)*D_ + 8*q;
        bf16x8 Ah0 = ldf(ap), Ah1 = ldf(ap+32), Al0 = ldf(alp), Al1 = ldf(alp+32);
        f32x4 z = {0.f,0.f,0.f,0.f};
        f32x4 acc[4] = {z,z,z,z};
        #pragma unroll
        for (int f = 0; f < 4; f++){
            acc[f] = mfma_bf16(Ah0, Bh[f][0], acc[f]);
            acc[f] = mfma_bf16(Ah0, Bl[f][0], acc[f]);
            acc[f] = mfma_bf16(Al0, Bh[f][0], acc[f]);
            acc[f] = mfma_bf16(Ah1, Bh[f][1], acc[f]);
            acc[f] = mfma_bf16(Ah1, Bl[f][1], acc[f]);
            acc[f] = mfma_bf16(Al1, Bh[f][1], acc[f]);
        }
        float rmv[4], riv[4];
        #pragma unroll
        for (int i = 0; i < 4; i++){
            int n = ns + 16*w + 4*q + i;
            rmv[i] = rmax[(size_t)b*N_ + n];
            riv[i] = 1.0f / rsum[(size_t)b*N_ + n];
        }
        #pragma unroll
        for (int f = 0; f < 4; f++){
            #pragma unroll
            for (int i = 0; i < 4; i++){
                float a = __expf(acc[f][i] - rmv[i]) * riv[i];
                csum[f] += a;
                tile[(16*f + r)*72 + 16*w + 4*q + i] = f2bf(a);
            }
        }
        __syncthreads();
        {
            int m = tid >> 2, j = tid & 3;
            uint4 v0 = *(uint4*)&tile[m*72 + 8*j];
            uint4 v1 = *(uint4*)&tile[m*72 + 8*(j+4)];
            *(uint4*)&ATb[(size_t)(m0 + m)*N_ + ns + 8*j] = v0;
            *(uint4*)&ATb[(size_t)(m0 + m)*N_ + ns + 32 + 8*j] = v1;
        }
        __syncthreads();
    }
    #pragma unroll
    for (int f = 0; f < 4; f++){
        float v = csum[f];
        v += __shfl_xor(v, 16);
        v += __shfl_xor(v, 32);
        if (q == 0) red[w][16*f + r] = v;
    }
    __syncthreads();
    if (tid < 64)
        colsum[(size_t)b*N_ + m0 + tid] = red[0][tid] + red[1][tid] + red[2][tid] + red[3][tid];
}

// ---------------------------------------------------------------------------
// xr: m97-style GEMM. Tile 128(c) x 64(m), BK=64, swizzled global_load_lds.
// u = x - xv*A/colsum, stored transposed uT [b][n][c] bf16.
__global__ __launch_bounds__(256) void xr_kernel(
    const unsigned short* __restrict__ xvb, const unsigned short* __restrict__ AT,
    const float* __restrict__ colsum, const float* __restrict__ x,
    unsigned short* __restrict__ uT, int b0)
{
    __shared__ unsigned short lds[12288];  // A: [0,8192) 128x64, B: [8192,12288) 64x64
    int bl = blockIdx.z, b = b0 + bl;
    int m0 = blockIdx.x * 64, c0 = blockIdx.y * 128;
    int tid = threadIdx.x, w = tid >> 6, lane = tid & 63, q = lane >> 4, r = lane & 15;
    int wr = w >> 1, wc = w & 1;
    int lrow = lane >> 3, lchunk = lane & 7;
    const unsigned short* Asrc = xvb + (size_t)b*C_*N_;   // [c][n]
    const unsigned short* Bsrc = AT + (size_t)bl*N_*N_;   // [m][n]
    f32x4 z = {0.f,0.f,0.f,0.f};
    f32x4 acc[4][2];
    #pragma unroll
    for (int rt = 0; rt < 4; rt++){ acc[rt][0] = z; acc[rt][1] = z; }
    for (int kt = 0; kt < N_/64; kt++){
        int k0 = kt*64;
        #pragma unroll
        for (int ri = 0; ri < 4; ri++){            // A: 128 rows, 4 rounds x 32 rows
            int row = ri*32 + w*8 + lrow;
            int sc = lchunk ^ (row & 7);
            gld_lds16(Asrc + (size_t)(c0 + row)*N_ + k0 + sc*8, &lds[ri*2048 + w*512]);
        }
        #pragma unroll
        for (int ri = 0; ri < 2; ri++){            // B: 64 rows, 2 rounds
            int row = ri*32 + w*8 + lrow;
            int sc = lchunk ^ (row & 7);
            gld_lds16(Bsrc + (size_t)(m0 + row)*N_ + k0 + sc*8, &lds[8192 + ri*2048 + w*512]);
        }
        __syncthreads();
        #pragma unroll
        for (int kc = 0; kc < 2; kc++){
            int sw = ((kc*4 + q) ^ (r & 7)) * 8;
            bf16x8 af[4], bfr[2];
            #pragma unroll
            for (int rt = 0; rt < 4; rt++)
                af[rt] = *(bf16x8*)&lds[(64*wr + 16*rt + r)*64 + sw];
            #pragma unroll
            for (int ct = 0; ct < 2; ct++)
                bfr[ct] = *(bf16x8*)&lds[8192 + (32*wc + 16*ct + r)*64 + sw];
            #pragma unroll
            for (int rt = 0; rt < 4; rt++)
                #pragma unroll
                for (int ct = 0; ct < 2; ct++)
                    acc[rt][ct] = mfma_bf16(af[rt], bfr[ct], acc[rt][ct]);
        }
        __syncthreads();
    }
    #pragma unroll
    for (int ct = 0; ct < 2; ct++){
        int m = m0 + 32*wc + 16*ct + r;
        float sc = 1.0f / (1e-9f + colsum[(size_t)b*N_ + m]);
        #pragma unroll
        for (int rt = 0; rt < 4; rt++){
            int cr = c0 + 64*wr + 16*rt + 4*q;
            float u0 = x[(size_t)(b*C_ + cr+0)*N_ + m] - acc[rt][ct][0]*sc;
            float u1 = x[(size_t)(b*C_ + cr+1)*N_ + m] - acc[rt][ct][1]*sc;
            float u2 = x[(size_t)(b*C_ + cr+2)*N_ + m] - acc[rt][ct][2]*sc;
            float u3 = x[(size_t)(b*C_ + cr+3)*N_ + m] - acc[rt][ct][3]*sc;
            ushort4 uv;
            uv.x = f2bf(u0); uv.y = f2bf(u1); uv.z = f2bf(u2); uv.w = f2bf(u3);
            *(ushort4*)&uT[((size_t)b*N_ + m)*C_ + cr] = uv;
        }
    }
}

// ---------------------------------------------------------------------------
// t-GEMM pass A: BN statistics only (bias bt cancels in training-mode BN)
__global__ __launch_bounds__(256) void t_stats_kernel(
    const unsigned short* __restrict__ uT, const unsigned short* __restrict__ Wtb,
    float* __restrict__ bnsum, float* __restrict__ bnsq)
{
    int b = blockIdx.z, n0 = blockIdx.x * 64, d0 = blockIdx.y * 64;
    int tid = threadIdx.x, w = tid >> 6, lane = tid & 63, q = lane >> 4, r = lane & 15;
    f32x4 z = {0.f,0.f,0.f,0.f};
    f32x4 acc[4] = {z,z,z,z};
    const unsigned short* A = Wtb + (size_t)(d0 + 16*w + r)*C_;
    const unsigned short* Bb = uT + ((size_t)(b*N_ + n0 + r))*C_;
    for (int k0 = 0; k0 < C_; k0 += 32){
        bf16x8 a = ldf(A + k0 + 8*q);
        #pragma unroll
        for (int f = 0; f < 4; f++){
            bf16x8 bb = ldf(Bb + (size_t)(16*f)*C_ + k0 + 8*q);
            acc[f] = mfma_bf16(a, bb, acc[f]);
        }
    }
    #pragma unroll
    for (int i = 0; i < 4; i++){
        float s = 0.f, s2 = 0.f;
        #pragma unroll
        for (int f = 0; f < 4; f++){ float v = acc[f][i]; s += v; s2 += v*v; }
        #pragma unroll
        for (int o = 1; o < 16; o <<= 1){ s += __shfl_xor(s, o); s2 += __shfl_xor(s2, o); }
        if (r == 0){
            int d = d0 + 16*w + 4*q + i;
            atomicAdd(&bnsum[d], s);
            atomicAdd(&bnsq[d], s2);
        }
    }
}

__global__ __launch_bounds__(256) void bn_final_kernel(
    const float* __restrict__ bnsum, const float* __restrict__ bnsq,
    const float* __restrict__ gamma, const float* __restrict__ beta,
    float* __restrict__ scale, float* __restrict__ shift)
{
    int d = threadIdx.x;
    const float inv = 1.0f / (B_ * N_);
    float m = bnsum[d] * inv;
    float v = bnsq[d] * inv - m*m;
    float rs = rsqrtf(v + 1e-5f);
    float sc = gamma[d] * rs;
    scale[d] = sc;
    shift[d] = beta[d] - m*sc;
}

// t-GEMM pass B: recompute t, apply BN + ReLU + residual, write out [b,d,n] fp32
__global__ __launch_bounds__(256) void final_kernel(
    const unsigned short* __restrict__ uT, const unsigned short* __restrict__ Wtb,
    const float* __restrict__ scale, const float* __restrict__ shift,
    const float* __restrict__ x, float* __restrict__ out)
{
    int b = blockIdx.z, n0 = blockIdx.x * 64, d0 = blockIdx.y * 64;
    int tid = threadIdx.x, w = tid >> 6, lane = tid & 63, q = lane >> 4, r = lane & 15;
    f32x4 z = {0.f,0.f,0.f,0.f};
    f32x4 acc[4] = {z,z,z,z};
    const unsigned short* A = Wtb + (size_t)(d0 + 16*w + r)*C_;
    const unsigned short* Bb = uT + ((size_t)(b*N_ + n0 + r))*C_;
    for (int k0 = 0; k0 < C_; k0 += 32){
        bf16x8 a = ldf(A + k0 + 8*q);
        #pragma unroll
        for (int f = 0; f < 4; f++){
            bf16x8 bb = ldf(Bb + (size_t)(16*f)*C_ + k0 + 8*q);
            acc[f] = mfma_bf16(a, bb, acc[f]);
        }
    }
    #pragma unroll
    for (int f = 0; f < 4; f++){
        int n = n0 + 16*f + r;
        #pragma unroll
        for (int i = 0; i < 4; i++){
            int d = d0 + 16*w + 4*q + i;
            float tv = acc[f][i]*scale[d] + shift[d];
            tv = fmaxf(tv, 0.0f);
            size_t o = ((size_t)(b*C_ + d))*N_ + n;
            out[o] = x[o] + tv;
        }
    }
}

// ---------------------------------------------------------------------------
extern "C" void kernel_launch(void* const* d_in, const int* in_sizes, int n_in,
                              void* d_out, int out_size, void* d_ws, size_t ws_size,
                              hipStream_t stream)
{
    const float* x     = (const float*)d_in[0];
    const float* Wqk   = (const float*)d_in[1];
    const float* Wv    = (const float*)d_in[2];
    const float* bv    = (const float*)d_in[3];
    const float* Wt    = (const float*)d_in[4];
    // d_in[5] = bt : cancels exactly through training-mode BatchNorm
    const float* gamma = (const float*)d_in[6];
    const float* beta  = (const float*)d_in[7];
    float* out = (float*)d_out;

    char* ws = (char*)d_ws;
    size_t off = 0;
    auto alloc = [&](size_t bytes) -> void* {
        void* p = ws + off;
        off += (bytes + 255) & ~(size_t)255;
        return p;
    };
    unsigned short* xhT    = (unsigned short*)alloc((size_t)B_*N_*C_*2);
    unsigned short* xlT    = (unsigned short*)alloc((size_t)B_*N_*C_*2);
    unsigned short* Wqk_hi = (unsigned short*)alloc((size_t)D_*C_*2);
    unsigned short* Wqk_lo = (unsigned short*)alloc((size_t)D_*C_*2);
    unsigned short* Wv_b   = (unsigned short*)alloc((size_t)C_*C_*2);
    unsigned short* Wt_b   = (unsigned short*)alloc((size_t)C_*C_*2);
    unsigned short* qh     = (unsigned short*)alloc((size_t)B_*N_*D_*2);
    unsigned short* ql     = (unsigned short*)alloc((size_t)B_*N_*D_*2);
    unsigned short* xvb    = (unsigned short*)alloc((size_t)B_*C_*N_*2);
    unsigned short* uT     = (unsigned short*)alloc((size_t)B_*N_*C_*2);
    unsigned short* AT     = (unsigned short*)alloc((size_t)GROUP_*N_*N_*2);
    float*          rmax   = (float*)alloc((size_t)B_*N_*4);
    float*          rsum   = (float*)alloc((size_t)B_*N_*4);
    float*          colsum = (float*)alloc((size_t)B_*N_*4);
    float*          bnsum  = (float*)alloc(256*4);
    float*          bnsq   = (float*)alloc(256*4);
    float*          scale  = (float*)alloc(256*4);
    float*          shift  = (float*)alloc(256*4);

    convert_x_kernel<<<dim3(N_/64, C_/64, B_), 256, 0, stream>>>(x, xhT, xlT);
    convert_w_kernel<<<(D_*C_ + 2*C_*C_ + 255)/256, 256, 0, stream>>>(
        Wqk, Wv, Wt, Wqk_hi, Wqk_lo, Wv_b, Wt_b);
    proj_qk_kernel<<<dim3(N_/64, 1, B_), 256, 0, stream>>>(xhT, xlT, Wqk_hi, Wqk_lo, qh, ql);
    proj_v_kernel<<<dim3(N_/64, C_/64, B_), 256, 0, stream>>>(xhT, Wv_b, bv, xvb);

    qk_stats_kernel<<<dim3(N_/64, B_), 256, 0, stream>>>(qh, ql, rmax, rsum);

    for (int g = 0; g < B_/GROUP_; g++){
        int b0 = g*GROUP_;
        colsum_at_kernel<<<dim3(N_/64, GROUP_), 256, 0, stream>>>(
            qh, ql, rmax, rsum, colsum, AT, b0);
        xr_kernel<<<dim3(N_/64, C_/128, GROUP_), 256, 0, stream>>>(
            xvb, AT, colsum, x, uT, b0);
    }

    hipMemsetAsync(bnsum, 0, 256*4, stream);
    hipMemsetAsync(bnsq, 0, 256*4, stream);
    t_stats_kernel<<<dim3(N_/64, C_/64, B_), 256, 0, stream>>>(uT, Wt_b, bnsum, bnsq);
    bn_final_kernel<<<1, 256, 0, stream>>>(bnsum, bnsq, gamma, beta, scale, shift);
    final_kernel<<<dim3(N_/64, C_/64, B_), 256, 0, stream>>>(uT, Wt_b, scale, shift, x, out);
}

// Round 3
// 694.920 us; speedup vs baseline: 2.1290x; 1.1795x over previous
//
#include <hip/hip_runtime.h>
#include <hip/hip_bf16.h>

#define B_ 8
#define C_ 256
#define N_ 4096
#define D_ 64
#define GROUP_ 4   // batches per attention group (AT sized for GROUP_ batches)

typedef __attribute__((ext_vector_type(8))) short bf16x8;
typedef __attribute__((ext_vector_type(4))) float f32x4;

__device__ __forceinline__ float bf2f(unsigned short h){
    return __uint_as_float(((unsigned int)h) << 16);
}
__device__ __forceinline__ unsigned short f2bf(float f){
    unsigned int u = __float_as_uint(f);
    u += 0x7FFFu + ((u >> 16) & 1u);
    return (unsigned short)(u >> 16);
}
__device__ __forceinline__ bf16x8 ldf(const unsigned short* p){
    return *(const bf16x8*)p;
}
__device__ __forceinline__ f32x4 mfma_bf16(bf16x8 a, bf16x8 b, f32x4 c){
    return __builtin_amdgcn_mfma_f32_16x16x32_bf16(a, b, c, 0, 0, 0);
}
__device__ __forceinline__ void gld_lds16(const unsigned short* g, unsigned short* l){
    __builtin_amdgcn_global_load_lds(
        (const __attribute__((address_space(1))) unsigned int*)g,
        (__attribute__((address_space(3))) unsigned int*)l, 16, 0, 0);
}

// ---------------------------------------------------------------------------
// x [B,C,N] fp32 -> xhT/xlT [B,N,C] bf16 hi/lo
__global__ __launch_bounds__(256) void convert_x_kernel(
    const float* __restrict__ x,
    unsigned short* __restrict__ xhT, unsigned short* __restrict__ xlT)
{
    __shared__ float tile[64][65];
    int b = blockIdx.z, c0 = blockIdx.y * 64, n0 = blockIdx.x * 64;
    int tid = threadIdx.x;
    int cc = tid & 63, rb = tid >> 6;
    #pragma unroll
    for (int j = 0; j < 16; j++){
        int rr = rb + 4*j;
        tile[rr][cc] = x[((size_t)(b*C_ + c0 + rr))*N_ + n0 + cc];
    }
    __syncthreads();
    #pragma unroll
    for (int j = 0; j < 16; j++){
        int rr = rb + 4*j;
        float v = tile[cc][rr];
        unsigned short h = f2bf(v);
        unsigned short l = f2bf(v - bf2f(h));
        size_t o = ((size_t)(b*N_ + n0 + rr))*C_ + c0 + cc;
        xhT[o] = h; xlT[o] = l;
    }
}

__global__ __launch_bounds__(256) void convert_w_kernel(
    const float* __restrict__ Wqk, const float* __restrict__ Wv, const float* __restrict__ Wt,
    unsigned short* __restrict__ Wqk_hi, unsigned short* __restrict__ Wqk_lo,
    unsigned short* __restrict__ Wv_b, unsigned short* __restrict__ Wt_b)
{
    int i = blockIdx.x * 256 + threadIdx.x;
    if (i < D_*C_){
        float v = Wqk[i];
        unsigned short h = f2bf(v);
        Wqk_hi[i] = h; Wqk_lo[i] = f2bf(v - bf2f(h));
    }
    int j = i - D_*C_;
    if (j >= 0 && j < C_*C_) Wv_b[j] = f2bf(Wv[j]);
    int k = j - C_*C_;
    if (k >= 0 && k < C_*C_) Wt_b[k] = f2bf(Wt[k]);
}

// qk[b,n,d]: split-bf16 3-term. Out [B,N,64] hi/lo
__global__ __launch_bounds__(256) void proj_qk_kernel(
    const unsigned short* __restrict__ xhT, const unsigned short* __restrict__ xlT,
    const unsigned short* __restrict__ Wh,  const unsigned short* __restrict__ Wl,
    unsigned short* __restrict__ qh, unsigned short* __restrict__ ql)
{
    int b = blockIdx.z, n0 = blockIdx.x * 64;
    int tid = threadIdx.x, w = tid >> 6, lane = tid & 63, q = lane >> 4, r = lane & 15;
    f32x4 z = {0.f,0.f,0.f,0.f};
    f32x4 acc[4] = {z,z,z,z};
    const unsigned short* Ah = Wh + (size_t)(16*w + r)*C_;
    const unsigned short* Al = Wl + (size_t)(16*w + r)*C_;
    const unsigned short* Bh = xhT + ((size_t)(b*N_ + n0 + r))*C_;
    const unsigned short* Bl = xlT + ((size_t)(b*N_ + n0 + r))*C_;
    for (int k0 = 0; k0 < C_; k0 += 32){
        bf16x8 ah = ldf(Ah + k0 + 8*q);
        bf16x8 al = ldf(Al + k0 + 8*q);
        #pragma unroll
        for (int f = 0; f < 4; f++){
            bf16x8 bh = ldf(Bh + (size_t)(16*f)*C_ + k0 + 8*q);
            bf16x8 bl = ldf(Bl + (size_t)(16*f)*C_ + k0 + 8*q);
            acc[f] = mfma_bf16(ah, bh, acc[f]);
            acc[f] = mfma_bf16(ah, bl, acc[f]);
            acc[f] = mfma_bf16(al, bh, acc[f]);
        }
    }
    #pragma unroll
    for (int f = 0; f < 4; f++){
        int col = n0 + 16*f + r;
        int d0 = 16*w + 4*q;
        size_t o = ((size_t)(b*N_ + col))*D_ + d0;
        ushort4 hv, lv;
        float v0 = acc[f][0], v1 = acc[f][1], v2 = acc[f][2], v3 = acc[f][3];
        hv.x = f2bf(v0); lv.x = f2bf(v0 - bf2f(hv.x));
        hv.y = f2bf(v1); lv.y = f2bf(v1 - bf2f(hv.y));
        hv.z = f2bf(v2); lv.z = f2bf(v2 - bf2f(hv.z));
        hv.w = f2bf(v3); lv.w = f2bf(v3 - bf2f(hv.w));
        *(ushort4*)(qh + o) = hv;
        *(ushort4*)(ql + o) = lv;
    }
}

// ---------------------------------------------------------------------------
// nrm[b,n] = ||q_n||  (wave per row)
__global__ __launch_bounds__(256) void qnorm_kernel(
    const unsigned short* __restrict__ qh, const unsigned short* __restrict__ ql,
    float* __restrict__ nrm)
{
    int rowg = blockIdx.x * 4 + (threadIdx.x >> 6);
    int lane = threadIdx.x & 63;
    float v = bf2f(qh[(size_t)rowg*D_ + lane]) + bf2f(ql[(size_t)rowg*D_ + lane]);
    float p = v*v;
    #pragma unroll
    for (int o = 1; o < 64; o <<= 1) p += __shfl_xor(p, o);
    if (lane == 0) nrm[rowg] = sqrtf(p);
}

// M[b] = max_n nrm[b,n]
__global__ __launch_bounds__(256) void qmax_kernel(
    const float* __restrict__ nrm, float* __restrict__ Mv)
{
    __shared__ float red[4];
    int b = blockIdx.x, tid = threadIdx.x, w = tid >> 6, lane = tid & 63;
    float m = 0.f;
    for (int i = tid; i < N_; i += 256) m = fmaxf(m, nrm[(size_t)b*N_ + i]);
    #pragma unroll
    for (int o = 1; o < 64; o <<= 1) m = fmaxf(m, __shfl_xor(m, o));
    if (lane == 0) red[w] = m;
    __syncthreads();
    if (tid == 0) Mv[b] = fmaxf(fmaxf(red[0], red[1]), fmaxf(red[2], red[3]));
}

// x_v'[b,d,n] = (Wv x + bv) * invrsum[n] -> xvb [B,C,N] bf16  (1/rsum folded in)
__global__ __launch_bounds__(256) void proj_v_kernel(
    const unsigned short* __restrict__ xhT, const unsigned short* __restrict__ Wvb,
    const float* __restrict__ bv, const float* __restrict__ invr,
    unsigned short* __restrict__ xvb, int b0)
{
    int b = b0 + blockIdx.z, n0 = blockIdx.x * 64, d0 = blockIdx.y * 64;
    int tid = threadIdx.x, w = tid >> 6, lane = tid & 63, q = lane >> 4, r = lane & 15;
    f32x4 z = {0.f,0.f,0.f,0.f};
    f32x4 acc[4] = {z,z,z,z};
    const unsigned short* A = Wvb + (size_t)(d0 + 16*w + r)*C_;
    const unsigned short* Bb = xhT + ((size_t)(b*N_ + n0 + r))*C_;
    for (int k0 = 0; k0 < C_; k0 += 32){
        bf16x8 a = ldf(A + k0 + 8*q);
        #pragma unroll
        for (int f = 0; f < 4; f++){
            bf16x8 bb = ldf(Bb + (size_t)(16*f)*C_ + k0 + 8*q);
            acc[f] = mfma_bf16(a, bb, acc[f]);
        }
    }
    #pragma unroll
    for (int f = 0; f < 4; f++){
        int col = n0 + 16*f + r;
        float iv = invr[(size_t)b*N_ + col];
        #pragma unroll
        for (int i = 0; i < 4; i++){
            int row = d0 + 16*w + 4*q + i;
            float v = (acc[f][i] + bv[row]) * iv;
            xvb[((size_t)(b*C_ + row))*N_ + col] = f2bf(v);
        }
    }
}

// ---------------------------------------------------------------------------
// ONE pass: energy (split-bf16, computed once), P = exp(e - nrm_n*M) -> AT[m][n],
// per-lane rsum partials (no in-loop shuffles). Grid (N/64, 4 m-splits, GROUP).
__global__ __launch_bounds__(256) void pstats_kernel(
    const unsigned short* __restrict__ qh, const unsigned short* __restrict__ ql,
    const float* __restrict__ nrm, const float* __restrict__ Mv,
    float* __restrict__ rsum_part, unsigned short* __restrict__ AT, int b0)
{
    __shared__ unsigned short tile[64*72];
    int n0 = blockIdx.x * 64, ms = blockIdx.y, bl = blockIdx.z, b = b0 + bl;
    int tid = threadIdx.x, w = tid >> 6, lane = tid & 63, q = lane >> 4, r = lane & 15;
    const unsigned short* qb = qh + (size_t)b*N_*D_;
    const unsigned short* lb = ql + (size_t)b*N_*D_;
    const unsigned short* ap  = qb + (size_t)(n0 + 16*w + r)*D_ + 8*q;
    const unsigned short* alp = lb + (size_t)(n0 + 16*w + r)*D_ + 8*q;
    bf16x8 Ah0 = ldf(ap), Ah1 = ldf(ap+32), Al0 = ldf(alp), Al1 = ldf(alp+32);
    float M = Mv[b];
    float4 nv = *(const float4*)&nrm[(size_t)b*N_ + n0 + 16*w + 4*q];
    float sh[4] = {nv.x*M, nv.y*M, nv.z*M, nv.w*M};
    float rs[4] = {0.f,0.f,0.f,0.f};
    unsigned short* ATb = AT + (size_t)bl*N_*N_;
    for (int mt = 0; mt < 16; mt++){
        int m0 = ms*1024 + mt*64;
        f32x4 z = {0.f,0.f,0.f,0.f};
        f32x4 acc[4] = {z,z,z,z};
        #pragma unroll
        for (int f = 0; f < 4; f++){
            const unsigned short* bp  = qb + (size_t)(m0 + 16*f + r)*D_ + 8*q;
            const unsigned short* blp = lb + (size_t)(m0 + 16*f + r)*D_ + 8*q;
            bf16x8 bh0 = ldf(bp), bh1 = ldf(bp+32);
            bf16x8 bl0 = ldf(blp), bl1 = ldf(blp+32);
            acc[f] = mfma_bf16(Ah0, bh0, acc[f]);
            acc[f] = mfma_bf16(Ah0, bl0, acc[f]);
            acc[f] = mfma_bf16(Al0, bh0, acc[f]);
            acc[f] = mfma_bf16(Ah1, bh1, acc[f]);
            acc[f] = mfma_bf16(Ah1, bl1, acc[f]);
            acc[f] = mfma_bf16(Al1, bh1, acc[f]);
        }
        #pragma unroll
        for (int f = 0; f < 4; f++){
            #pragma unroll
            for (int i = 0; i < 4; i++){
                float p = __expf(acc[f][i] - sh[i]);
                rs[i] += p;
                tile[(16*f + r)*72 + 16*w + 4*q + i] = f2bf(p);
            }
        }
        __syncthreads();
        {
            int m = tid >> 2, j = tid & 3;
            uint4 v0 = *(uint4*)&tile[m*72 + 8*j];
            uint4 v1 = *(uint4*)&tile[m*72 + 8*(j+4)];
            *(uint4*)&ATb[(size_t)(m0 + m)*N_ + n0 + 8*j] = v0;
            *(uint4*)&ATb[(size_t)(m0 + m)*N_ + n0 + 32 + 8*j] = v1;
        }
        __syncthreads();
    }
    #pragma unroll
    for (int i = 0; i < 4; i++){
        #pragma unroll
        for (int o = 1; o < 16; o <<= 1) rs[i] += __shfl_xor(rs[i], o);
    }
    if (r == 0){
        float4 v; v.x = rs[0]; v.y = rs[1]; v.z = rs[2]; v.w = rs[3];
        *(float4*)&rsum_part[((size_t)ms*B_ + b)*N_ + n0 + 16*w + 4*q] = v;
    }
}

// invr[b,n] = 1 / sum_s rsum_part[s][b][n]
__global__ __launch_bounds__(256) void invfin_kernel(
    const float* __restrict__ rsum_part, float* __restrict__ invr, int b0)
{
    int gi = blockIdx.x * 256 + threadIdx.x;
    int bl = gi / N_, n = gi - bl*N_;
    size_t o = (size_t)(b0 + bl)*N_ + n;
    float s = rsum_part[o] + rsum_part[(size_t)B_*N_ + o]
            + rsum_part[(size_t)2*B_*N_ + o] + rsum_part[(size_t)3*B_*N_ + o];
    invr[o] = 1.0f / s;
}

// colsum[b,m] = sum_n P[n,m] * invr[n]   (AT is [m][n], L3-resident)
__global__ __launch_bounds__(256) void csum_kernel(
    const unsigned short* __restrict__ AT, const float* __restrict__ invr,
    float* __restrict__ colsum, int b0)
{
    int m0 = blockIdx.x * 64, bl = blockIdx.y, b = b0 + bl;
    int tid = threadIdx.x, w = tid >> 6, lane = tid & 63;
    const unsigned short* ATb = AT + (size_t)bl*N_*N_;
    const float* iv = invr + (size_t)b*N_;
    for (int rr = 0; rr < 16; rr++){
        int m = m0 + w*16 + rr;
        const unsigned short* row = ATb + (size_t)m*N_;
        float s = 0.f;
        #pragma unroll
        for (int ch = 0; ch < 8; ch++){
            int n = ch*512 + lane*8;
            bf16x8 p = ldf(row + n);
            float4 i0 = *(const float4*)&iv[n];
            float4 i1 = *(const float4*)&iv[n+4];
            s += bf2f((unsigned short)p[0])*i0.x + bf2f((unsigned short)p[1])*i0.y
               + bf2f((unsigned short)p[2])*i0.z + bf2f((unsigned short)p[3])*i0.w
               + bf2f((unsigned short)p[4])*i1.x + bf2f((unsigned short)p[5])*i1.y
               + bf2f((unsigned short)p[6])*i1.z + bf2f((unsigned short)p[7])*i1.w;
        }
        #pragma unroll
        for (int o = 1; o < 64; o <<= 1) s += __shfl_xor(s, o);
        if (lane == 0) colsum[(size_t)b*N_ + m] = s;
    }
}

// ---------------------------------------------------------------------------
// xr: tile 128(c) x 64(m), BK=64, swizzled global_load_lds.
// u = x - (xv' * P)/colsum, stored transposed uT [b][n][c] bf16.
__global__ __launch_bounds__(256) void xr_kernel(
    const unsigned short* __restrict__ xvb, const unsigned short* __restrict__ AT,
    const float* __restrict__ colsum, const float* __restrict__ x,
    unsigned short* __restrict__ uT, int b0)
{
    __shared__ unsigned short lds[12288];
    int bl = blockIdx.z, b = b0 + bl;
    int m0 = blockIdx.x * 64, c0 = blockIdx.y * 128;
    int tid = threadIdx.x, w = tid >> 6, lane = tid & 63, q = lane >> 4, r = lane & 15;
    int wr = w >> 1, wc = w & 1;
    int lrow = lane >> 3, lchunk = lane & 7;
    const unsigned short* Asrc = xvb + (size_t)b*C_*N_;
    const unsigned short* Bsrc = AT + (size_t)bl*N_*N_;
    f32x4 z = {0.f,0.f,0.f,0.f};
    f32x4 acc[4][2];
    #pragma unroll
    for (int rt = 0; rt < 4; rt++){ acc[rt][0] = z; acc[rt][1] = z; }
    for (int kt = 0; kt < N_/64; kt++){
        int k0 = kt*64;
        #pragma unroll
        for (int ri = 0; ri < 4; ri++){
            int row = ri*32 + w*8 + lrow;
            int sc = lchunk ^ (row & 7);
            gld_lds16(Asrc + (size_t)(c0 + row)*N_ + k0 + sc*8, &lds[ri*2048 + w*512]);
        }
        #pragma unroll
        for (int ri = 0; ri < 2; ri++){
            int row = ri*32 + w*8 + lrow;
            int sc = lchunk ^ (row & 7);
            gld_lds16(Bsrc + (size_t)(m0 + row)*N_ + k0 + sc*8, &lds[8192 + ri*2048 + w*512]);
        }
        __syncthreads();
        #pragma unroll
        for (int kc = 0; kc < 2; kc++){
            int sw = ((kc*4 + q) ^ (r & 7)) * 8;
            bf16x8 af[4], bfr[2];
            #pragma unroll
            for (int rt = 0; rt < 4; rt++)
                af[rt] = *(bf16x8*)&lds[(64*wr + 16*rt + r)*64 + sw];
            #pragma unroll
            for (int ct = 0; ct < 2; ct++)
                bfr[ct] = *(bf16x8*)&lds[8192 + (32*wc + 16*ct + r)*64 + sw];
            #pragma unroll
            for (int rt = 0; rt < 4; rt++)
                #pragma unroll
                for (int ct = 0; ct < 2; ct++)
                    acc[rt][ct] = mfma_bf16(af[rt], bfr[ct], acc[rt][ct]);
        }
        __syncthreads();
    }
    #pragma unroll
    for (int ct = 0; ct < 2; ct++){
        int m = m0 + 32*wc + 16*ct + r;
        float sc = 1.0f / (1e-9f + colsum[(size_t)b*N_ + m]);
        #pragma unroll
        for (int rt = 0; rt < 4; rt++){
            int cr = c0 + 64*wr + 16*rt + 4*q;
            float u0 = x[(size_t)(b*C_ + cr+0)*N_ + m] - acc[rt][ct][0]*sc;
            float u1 = x[(size_t)(b*C_ + cr+1)*N_ + m] - acc[rt][ct][1]*sc;
            float u2 = x[(size_t)(b*C_ + cr+2)*N_ + m] - acc[rt][ct][2]*sc;
            float u3 = x[(size_t)(b*C_ + cr+3)*N_ + m] - acc[rt][ct][3]*sc;
            ushort4 uv;
            uv.x = f2bf(u0); uv.y = f2bf(u1); uv.z = f2bf(u2); uv.w = f2bf(u3);
            *(ushort4*)&uT[((size_t)b*N_ + m)*C_ + cr] = uv;
        }
    }
}

// ---------------------------------------------------------------------------
__global__ __launch_bounds__(256) void t_stats_kernel(
    const unsigned short* __restrict__ uT, const unsigned short* __restrict__ Wtb,
    float* __restrict__ bnsum, float* __restrict__ bnsq)
{
    int b = blockIdx.z, n0 = blockIdx.x * 64, d0 = blockIdx.y * 64;
    int tid = threadIdx.x, w = tid >> 6, lane = tid & 63, q = lane >> 4, r = lane & 15;
    f32x4 z = {0.f,0.f,0.f,0.f};
    f32x4 acc[4] = {z,z,z,z};
    const unsigned short* A = Wtb + (size_t)(d0 + 16*w + r)*C_;
    const unsigned short* Bb = uT + ((size_t)(b*N_ + n0 + r))*C_;
    for (int k0 = 0; k0 < C_; k0 += 32){
        bf16x8 a = ldf(A + k0 + 8*q);
        #pragma unroll
        for (int f = 0; f < 4; f++){
            bf16x8 bb = ldf(Bb + (size_t)(16*f)*C_ + k0 + 8*q);
            acc[f] = mfma_bf16(a, bb, acc[f]);
        }
    }
    #pragma unroll
    for (int i = 0; i < 4; i++){
        float s = 0.f, s2 = 0.f;
        #pragma unroll
        for (int f = 0; f < 4; f++){ float v = acc[f][i]; s += v; s2 += v*v; }
        #pragma unroll
        for (int o = 1; o < 16; o <<= 1){ s += __shfl_xor(s, o); s2 += __shfl_xor(s2, o); }
        if (r == 0){
            int d = d0 + 16*w + 4*q + i;
            atomicAdd(&bnsum[d], s);
            atomicAdd(&bnsq[d], s2);
        }
    }
}

__global__ __launch_bounds__(256) void bn_final_kernel(
    const float* __restrict__ bnsum, const float* __restrict__ bnsq,
    const float* __restrict__ gamma, const float* __restrict__ beta,
    float* __restrict__ scale, float* __restrict__ shift)
{
    int d = threadIdx.x;
    const float inv = 1.0f / (B_ * N_);
    float m = bnsum[d] * inv;
    float v = bnsq[d] * inv - m*m;
    float rs = rsqrtf(v + 1e-5f);
    float sc = gamma[d] * rs;
    scale[d] = sc;
    shift[d] = beta[d] - m*sc;
}

__global__ __launch_bounds__(256) void final_kernel(
    const unsigned short* __restrict__ uT, const unsigned short* __restrict__ Wtb,
    const float* __restrict__ scale, const float* __restrict__ shift,
    const float* __restrict__ x, float* __restrict__ out)
{
    int b = blockIdx.z, n0 = blockIdx.x * 64, d0 = blockIdx.y * 64;
    int tid = threadIdx.x, w = tid >> 6, lane = tid & 63, q = lane >> 4, r = lane & 15;
    f32x4 z = {0.f,0.f,0.f,0.f};
    f32x4 acc[4] = {z,z,z,z};
    const unsigned short* A = Wtb + (size_t)(d0 + 16*w + r)*C_;
    const unsigned short* Bb = uT + ((size_t)(b*N_ + n0 + r))*C_;
    for (int k0 = 0; k0 < C_; k0 += 32){
        bf16x8 a = ldf(A + k0 + 8*q);
        #pragma unroll
        for (int f = 0; f < 4; f++){
            bf16x8 bb = ldf(Bb + (size_t)(16*f)*C_ + k0 + 8*q);
            acc[f] = mfma_bf16(a, bb, acc[f]);
        }
    }
    #pragma unroll
    for (int f = 0; f < 4; f++){
        int n = n0 + 16*f + r;
        #pragma unroll
        for (int i = 0; i < 4; i++){
            int d = d0 + 16*w + 4*q + i;
            float tv = acc[f][i]*scale[d] + shift[d];
            tv = fmaxf(tv, 0.0f);
            size_t o = ((size_t)(b*C_ + d))*N_ + n;
            out[o] = x[o] + tv;
        }
    }
}

// ---------------------------------------------------------------------------
extern "C" void kernel_launch(void* const* d_in, const int* in_sizes, int n_in,
                              void* d_out, int out_size, void* d_ws, size_t ws_size,
                              hipStream_t stream)
{
    const float* x     = (const float*)d_in[0];
    const float* Wqk   = (const float*)d_in[1];
    const float* Wv    = (const float*)d_in[2];
    const float* bv    = (const float*)d_in[3];
    const float* Wt    = (const float*)d_in[4];
    // d_in[5] = bt : cancels exactly through training-mode BatchNorm
    const float* gamma = (const float*)d_in[6];
    const float* beta  = (const float*)d_in[7];
    float* out = (float*)d_out;

    char* ws = (char*)d_ws;
    size_t off = 0;
    auto alloc = [&](size_t bytes) -> void* {
        void* p = ws + off;
        off += (bytes + 255) & ~(size_t)255;
        return p;
    };
    unsigned short* xhT    = (unsigned short*)alloc((size_t)B_*N_*C_*2);
    unsigned short* xlT    = (unsigned short*)alloc((size_t)B_*N_*C_*2);
    unsigned short* Wqk_hi = (unsigned short*)alloc((size_t)D_*C_*2);
    unsigned short* Wqk_lo = (unsigned short*)alloc((size_t)D_*C_*2);
    unsigned short* Wv_b   = (unsigned short*)alloc((size_t)C_*C_*2);
    unsigned short* Wt_b   = (unsigned short*)alloc((size_t)C_*C_*2);
    unsigned short* qh     = (unsigned short*)alloc((size_t)B_*N_*D_*2);
    unsigned short* ql     = (unsigned short*)alloc((size_t)B_*N_*D_*2);
    unsigned short* xvb    = (unsigned short*)alloc((size_t)B_*C_*N_*2);
    unsigned short* uT     = (unsigned short*)alloc((size_t)B_*N_*C_*2);
    unsigned short* AT     = (unsigned short*)alloc((size_t)GROUP_*N_*N_*2);
    float*          nrm    = (float*)alloc((size_t)B_*N_*4);
    float*          Mv     = (float*)alloc(B_*4);
    float*          rsum_part = (float*)alloc((size_t)4*B_*N_*4);
    float*          invr   = (float*)alloc((size_t)B_*N_*4);
    float*          colsum = (float*)alloc((size_t)B_*N_*4);
    float*          bnsum  = (float*)alloc(256*4);
    float*          bnsq   = (float*)alloc(256*4);
    float*          scale  = (float*)alloc(256*4);
    float*          shiftb = (float*)alloc(256*4);

    convert_x_kernel<<<dim3(N_/64, C_/64, B_), 256, 0, stream>>>(x, xhT, xlT);
    convert_w_kernel<<<(D_*C_ + 2*C_*C_ + 255)/256, 256, 0, stream>>>(
        Wqk, Wv, Wt, Wqk_hi, Wqk_lo, Wv_b, Wt_b);
    proj_qk_kernel<<<dim3(N_/64, 1, B_), 256, 0, stream>>>(xhT, xlT, Wqk_hi, Wqk_lo, qh, ql);
    qnorm_kernel<<<(B_*N_)/4, 256, 0, stream>>>(qh, ql, nrm);
    qmax_kernel<<<B_, 256, 0, stream>>>(nrm, Mv);

    for (int g = 0; g < B_/GROUP_; g++){
        int b0 = g*GROUP_;
        pstats_kernel<<<dim3(N_/64, 4, GROUP_), 256, 0, stream>>>(
            qh, ql, nrm, Mv, rsum_part, AT, b0);
        invfin_kernel<<<(GROUP_*N_)/256, 256, 0, stream>>>(rsum_part, invr, b0);
        csum_kernel<<<dim3(N_/64, GROUP_), 256, 0, stream>>>(AT, invr, colsum, b0);
        proj_v_kernel<<<dim3(N_/64, C_/64, GROUP_), 256, 0, stream>>>(
            xhT, Wv_b, bv, invr, xvb, b0);
        xr_kernel<<<dim3(N_/64, C_/128, GROUP_), 256, 0, stream>>>(
            xvb, AT, colsum, x, uT, b0);
    }

    hipMemsetAsync(bnsum, 0, 256*4, stream);
    hipMemsetAsync(bnsq, 0, 256*4, stream);
    t_stats_kernel<<<dim3(N_/64, C_/64, B_), 256, 0, stream>>>(uT, Wt_b, bnsum, bnsq);
    bn_final_kernel<<<1, 256, 0, stream>>>(bnsum, bnsq, gamma, beta, scale, shiftb);
    final_kernel<<<dim3(N_/64, C_/64, B_), 256, 0, stream>>>(uT, Wt_b, scale, shiftb, x, out);
}